// Round 5
// baseline (112.257 us; speedup 1.0000x reference)
//
#include <hip/hip_runtime.h>
#include <hip/hip_cooperative_groups.h>
#include <math.h>

namespace cg = cooperative_groups;

#define N_B 16
#define C_CH 128
#define T_LEN 513
#define NI 257
#define NJ 256
#define NIB 17
#define SCALE (1.4426950408889634f/128.0f)     // log2(e)/C

// float-unit offsets in workspace
#define RAM_OFF 0                              // f32 [16][257][256]
#define PDA_OFF (N_B*NI*NJ)                    // f32 [16][17][256]
#define P_OFF   (PDA_OFF + N_B*NIB*NJ)         // f32 [16][2][288]  (c-half partials)
#define Q_OFF   (P_OFF + N_B*2*288)            // f32 [16][2][256]
#define AH_OFF  (Q_OFF + N_B*2*256)            // u16 [16][288][128]
#define AL_OFF  (AH_OFF + N_B*288*64)
#define BH_OFF  (AL_OFF + N_B*288*64)          // u16 [16][256][128]
#define BL_OFF  (BH_OFF + N_B*256*64)
// total 2,253,824 floats ~= 9.0 MB

typedef unsigned short u16;
typedef u16 u16x8 __attribute__((ext_vector_type(8)));
typedef short bf16x8 __attribute__((ext_vector_type(8)));
typedef float f32x4 __attribute__((ext_vector_type(4)));

__device__ inline u16 bf16_rne(float f) {
    unsigned u = __builtin_bit_cast(unsigned, f);
    return (u16)((u + 0x7fffu + ((u >> 16) & 1u)) >> 16);
}

__global__ __launch_bounds__(256, 2) void k_fused(const float* __restrict__ x,
                                                  float* __restrict__ ws,
                                                  float* __restrict__ out) {
    float* ram = ws + RAM_OFF;
    float* pda = ws + PDA_OFF;
    float* Pp  = ws + P_OFF;
    float* Qp  = ws + Q_OFF;
    u16* Ah = (u16*)(ws + AH_OFF);
    u16* Al = (u16*)(ws + AL_OFF);
    u16* Bh = (u16*)(ws + BH_OFF);
    u16* Bl = (u16*)(ws + BL_OFF);

    __shared__ float smem[64 * 65];
    const int bid = blockIdx.x, tid = threadIdx.x;
    cg::grid_group grid = cg::this_grid();

    // ---------- Phase A: transpose x -> t-major bf16 hi/lo planes + P/Q partials.
    // 288 units: (n, t-chunk-of-64, c-half-of-64). Blocks 0..15 run two units.
    for (int u = bid; u < 288; u += 272) {
        const int n = u / 18, r2 = u % 18;
        const int t0 = (r2 >> 1) * 64, ch = (r2 & 1) * 64;
        float (*s)[65] = (float (*)[65])smem;
        {
            const int tt = tid & 63, w = tid >> 6;
            const float* xp = x + (size_t)n * (C_CH * T_LEN) + (size_t)ch * T_LEN + t0 + tt;
            const bool ok = (t0 + tt) < T_LEN;
            #pragma unroll
            for (int k = 0; k < 16; ++k) {
                const int cl = w * 16 + k;
                s[tt][cl] = ok ? xp[(size_t)cl * T_LEN] : 0.f;   // zero-pads t>=513
            }
        }
        __syncthreads();
        {
            const int r = tid >> 2, cq = (tid & 3) * 16;
            const int t = t0 + r, row = t >> 1;                  // row <= 287
            const bool isA = (t & 1) == 0;
            float fsq = 0.f;
            u16x8 hv[2], lv[2];
            #pragma unroll
            for (int q = 0; q < 2; ++q) {
                #pragma unroll
                for (int e = 0; e < 8; ++e) {
                    const float f = s[r][cq + 8 * q + e];
                    const u16 hb = bf16_rne(f);
                    const float hf = __builtin_bit_cast(float, (unsigned)hb << 16);
                    hv[q][e] = hb;
                    lv[q][e] = bf16_rne(f - hf);
                    fsq = fmaf(f, f, fsq);
                }
            }
            if (isA) {
                const size_t off = ((size_t)n * 288 + row) * 128 + ch + cq;
                *(u16x8*)(Ah + off) = hv[0]; *(u16x8*)(Ah + off + 8) = hv[1];
                *(u16x8*)(Al + off) = lv[0]; *(u16x8*)(Al + off + 8) = lv[1];
            } else if (row < 256) {
                const size_t off = ((size_t)n * 256 + row) * 128 + ch + cq;
                *(u16x8*)(Bh + off) = hv[0]; *(u16x8*)(Bh + off + 8) = hv[1];
                *(u16x8*)(Bl + off) = lv[0]; *(u16x8*)(Bl + off + 8) = lv[1];
            }
            fsq += __shfl_xor(fsq, 1, 64);
            fsq += __shfl_xor(fsq, 2, 64);
            if ((tid & 3) == 0) {
                const int h = ch >> 6;
                if (isA) Pp[((size_t)n * 2 + h) * 288 + row] = fsq;   // pads get 0
                else if (row < 256) Qp[((size_t)n * 2 + h) * 256 + row] = fsq;
            }
        }
        __syncthreads();
    }

    grid.sync();

    // ---------- Phase B: 4 j-tiles per wave sharing one A-fragment load.
    // 1088 waves x 4 tiles = 4352 16x16 tiles. 12 MFMAs/tile (hi*hi+hi*lo+lo*hi).
    {
        const int gw = bid * 4 + (tid >> 6);
        const int base = gw * 4;                     // 4 consecutive tiles, same (n, ib)
        const int n = base / 272, rem = base % 272;
        const int ib = rem >> 4, jb0 = rem & 15;     // jb0 in {0,4,8,12}
        const int i0 = ib * 16;
        const int l = tid & 63, il = l & 15, g = l >> 4;
        const size_t arow = ((size_t)n * 288 + i0 + il) * 128 + 8 * g;
        bf16x8 ah[4], al[4];
        #pragma unroll
        for (int kc = 0; kc < 4; ++kc) {
            ah[kc] = *(const bf16x8*)(Ah + arow + 32 * kc);
            al[kc] = *(const bf16x8*)(Al + arow + 32 * kc);
        }
        const float4 pA = *(const float4*)&Pp[((size_t)n * 2 + 0) * 288 + i0 + 4 * g];
        const float4 pB = *(const float4*)&Pp[((size_t)n * 2 + 1) * 288 + i0 + 4 * g];
        const float pv[4] = {pA.x + pB.x, pA.y + pB.y, pA.z + pB.z, pA.w + pB.w};
        float* rn = ram + (size_t)n * NI * NJ;
        #pragma unroll
        for (int jj = 0; jj < 4; ++jj) {
            const int j0 = (jb0 + jj) * 16;
            const size_t brow = ((size_t)n * 256 + j0 + il) * 128 + 8 * g;
            f32x4 acc = {0.f, 0.f, 0.f, 0.f};
            #pragma unroll
            for (int kc = 0; kc < 4; ++kc) {
                const bf16x8 bh = *(const bf16x8*)(Bh + brow + 32 * kc);
                const bf16x8 bl = *(const bf16x8*)(Bl + brow + 32 * kc);
                acc = __builtin_amdgcn_mfma_f32_16x16x32_bf16(ah[kc], bh, acc, 0, 0, 0);
                acc = __builtin_amdgcn_mfma_f32_16x16x32_bf16(ah[kc], bl, acc, 0, 0, 0);
                acc = __builtin_amdgcn_mfma_f32_16x16x32_bf16(al[kc], bh, acc, 0, 0, 0);
            }
            const float qv = Qp[((size_t)n * 2 + 0) * 256 + j0 + il]
                           + Qp[((size_t)n * 2 + 1) * 256 + j0 + il];
            float cs = 0.f;
            #pragma unroll
            for (int r = 0; r < 4; ++r) {
                const int i = i0 + 4 * g + r;
                const float Sv = pv[r] + qv - 2.f * acc[r];
                const float rv = exp2f(Sv * SCALE);   // RAM >= 1 -> 0.5-threshold dead
                if (i < NI) { rn[(size_t)i * NJ + j0 + il] = rv; cs += rv; }
            }
            cs += __shfl_xor(cs, 16, 64);
            cs += __shfl_xor(cs, 32, 64);
            if (l < 16) pda[((size_t)n * NIB + ib) * NJ + j0 + l] = cs;
        }
    }

    grid.sync();

    // ---------- Phase C: w_j = rsqrt(da_j); per-row db + rowsum; fused apply.
    {
        const int n = bid / NIB, ic = bid % NIB;
        float* w_s = smem;
        float* f_s = smem + 256;
        {
            float da = 0.f;
            #pragma unroll
            for (int k = 0; k < NIB; ++k) da += pda[((size_t)n * NIB + k) * NJ + tid];
            w_s[tid] = rsqrtf(da);                   // da >= 257, eps negligible
        }
        __syncthreads();
        const int wv = tid >> 6, lane = tid & 63;
        #pragma unroll
        for (int rr = 0; rr < 4; ++rr) {
            const int lr = wv * 4 + rr;
            const int i = ic * 16 + lr;
            if (i < NI) {
                const float* rrow = ram + ((size_t)n * NI + i) * NJ;
                float db = 0.f, t0 = 0.f;
                #pragma unroll
                for (int k = 0; k < 4; ++k) {
                    const float v = rrow[lane + 64 * k];
                    db += v;
                    t0 = fmaf(v, w_s[lane + 64 * k], t0);
                }
                #pragma unroll
                for (int off = 32; off; off >>= 1) {
                    db += __shfl_xor(db, off, 64);
                    t0 += __shfl_xor(t0, off, 64);
                }
                if (lane == 0) f_s[lr] = 2.f * t0 * rsqrtf(db);
            }
        }
        __syncthreads();
        const int tt = tid & 31, cgp = tid >> 5;
        const int t = ic * 32 + tt;
        if (t < T_LEN) {
            const float f = f_s[tt >> 1];
            const float* xn = x + (size_t)n * C_CH * T_LEN + t;
            float* on = out + (size_t)n * C_CH * T_LEN + t;
            #pragma unroll
            for (int p = 0; p < 16; ++p) {
                const int c = p * 8 + cgp;
                on[(size_t)c * T_LEN] = xn[(size_t)c * T_LEN] * f;
            }
        }
    }
}

extern "C" void kernel_launch(void* const* d_in, const int* in_sizes, int n_in,
                              void* d_out, int out_size, void* d_ws, size_t ws_size,
                              hipStream_t stream) {
    const float* x = (const float*)d_in[0];
    float* out = (float*)d_out;
    float* ws = (float*)d_ws;
    void* args[] = { (void*)&x, (void*)&ws, (void*)&out };
    hipLaunchCooperativeKernel((const void*)k_fused, dim3(272), dim3(256),
                               args, 0, stream);
}

// Round 7
// 40.482 us; speedup vs baseline: 2.7730x; 2.7730x over previous
//
#include <hip/hip_runtime.h>
#include <math.h>

#define N_B 16
#define C_CH 128
#define T_LEN 513
#define NI 257
#define NJ 256
#define SCALE (1.4426950408889634f/128.0f)     // log2(e)/C

typedef unsigned u32;
typedef unsigned short u16;
typedef short bf16x8 __attribute__((ext_vector_type(8)));
typedef float f32x4 __attribute__((ext_vector_type(4)));

// workspace: pda f32 [16][17][256] = 69,632 floats (279 KB)

__device__ inline u16 bf16_rne(float f) {
    const u32 u = __builtin_bit_cast(u32, f);
    return (u16)((u + 0x7fffu + ((u >> 16) & 1u)) >> 16);
}

__device__ inline void cvt8(float4 f0, float4 f1, bf16x8& hv, bf16x8& lv) {
    const float fs[8] = {f0.x, f0.y, f0.z, f0.w, f1.x, f1.y, f1.z, f1.w};
    union { u32 w[4]; bf16x8 v; } H, L;
    #pragma unroll
    for (int p = 0; p < 4; ++p) {
        const float a = fs[2*p], b = fs[2*p+1];
        const u16 ha = bf16_rne(a), hb = bf16_rne(b);
        const float ra = a - __builtin_bit_cast(float, (u32)ha << 16);
        const float rb = b - __builtin_bit_cast(float, (u32)hb << 16);
        const u16 la = bf16_rne(ra), lb = bf16_rne(rb);
        H.w[p] = (u32)ha | ((u32)hb << 16);
        L.w[p] = (u32)la | ((u32)lb << 16);
    }
    hv = H.v; lv = L.v;
}

__device__ inline float dot8(float4 a, float4 b) {
    return a.x*a.x + a.y*a.y + a.z*a.z + a.w*a.w
         + b.x*b.x + b.y*b.y + b.z*b.z + b.w*b.w;
}

// ---------------- K1: per (n, ib): compute RAM tiles, write pda column partials only.
__global__ __launch_bounds__(256) void k1(const float* __restrict__ x,
                                          float* __restrict__ pda) {
    __shared__ float Araw[16][132];
    __shared__ float Braw[64][132];
    const int bid = blockIdx.x;
    const int n = bid / 17, ib = bid % 17;
    const int i0 = ib * 16;
    const int tid = threadIdx.x;
    const float* xn = x + (size_t)n * C_CH * T_LEN;

    // stage A rows (even t in [2*i0, 2*i0+32)), zero-padded past t=512
    {
        const int u = tid & 31, cg8 = tid >> 5;
        const int t = 2 * i0 + u;
        #pragma unroll
        for (int p = 0; p < 16; ++p) {
            const int c = cg8 * 16 + p;
            const float v = (t <= 512) ? xn[c * T_LEN + t] : 0.f;
            if (!(u & 1)) Araw[u >> 1][c] = v;
        }
    }
    __syncthreads();

    const int l = tid & 63, wv = tid >> 6, il = l & 15, g = l >> 4;
    // A fragments (per wave) + exact fp32 P
    bf16x8 ah[4], al[4];
    float psum = 0.f;
    #pragma unroll
    for (int kc = 0; kc < 4; ++kc) {
        const float* ap = &Araw[il][32 * kc + 8 * g];
        const float4 f0 = *(const float4*)ap, f1 = *(const float4*)(ap + 4);
        psum += dot8(f0, f1);
        cvt8(f0, f1, ah[kc], al[kc]);
    }
    psum += __shfl_xor(psum, 16, 64);
    psum += __shfl_xor(psum, 32, 64);          // P[il] replicated
    float pv[4];
    #pragma unroll
    for (int r = 0; r < 4; ++r) pv[r] = __shfl(psum, 4 * g + r, 64);

    for (int ch = 0; ch < 4; ++ch) {
        __syncthreads();                        // prior chunk's Braw reads done
        {   // stage B chunk: odd t in [128*ch, 128*ch+128)
            const int u = tid & 31, cg8 = tid >> 5;
            #pragma unroll
            for (int p = 0; p < 16; ++p) {
                const int c = cg8 * 16 + p;
                #pragma unroll
                for (int s = 0; s < 4; ++s) {
                    const int uu = u + 32 * s;
                    const float v = xn[c * T_LEN + 128 * ch + uu];
                    if (uu & 1) Braw[uu >> 1][c] = v;
                }
            }
        }
        __syncthreads();
        // B fragments (wave's own 16-col tile) + exact Q
        bf16x8 bh[4], bl[4];
        float qsq = 0.f;
        #pragma unroll
        for (int kc = 0; kc < 4; ++kc) {
            const float* bp = &Braw[16 * wv + il][32 * kc + 8 * g];
            const float4 f0 = *(const float4*)bp, f1 = *(const float4*)(bp + 4);
            qsq += dot8(f0, f1);
            cvt8(f0, f1, bh[kc], bl[kc]);
        }
        qsq += __shfl_xor(qsq, 16, 64);
        qsq += __shfl_xor(qsq, 32, 64);         // Q[col il] replicated

        f32x4 acc = {0.f, 0.f, 0.f, 0.f};
        #pragma unroll
        for (int kc = 0; kc < 4; ++kc) {
            acc = __builtin_amdgcn_mfma_f32_16x16x32_bf16(ah[kc], bh[kc], acc, 0, 0, 0);
            acc = __builtin_amdgcn_mfma_f32_16x16x32_bf16(ah[kc], bl[kc], acc, 0, 0, 0);
            acc = __builtin_amdgcn_mfma_f32_16x16x32_bf16(al[kc], bh[kc], acc, 0, 0, 0);
        }
        float cs = 0.f;
        #pragma unroll
        for (int r = 0; r < 4; ++r) {
            const int i = i0 + 4 * g + r;
            const float rv = exp2f((pv[r] + qsq - 2.f * acc[r]) * SCALE);
            if (i < NI) cs += rv;               // RAM >= 1: 0.5-threshold is dead code
        }
        cs += __shfl_xor(cs, 16, 64);
        cs += __shfl_xor(cs, 32, 64);
        if (l < 16) pda[((size_t)n * 17 + ib) * NJ + 64 * ch + 16 * wv + l] = cs;
    }
}

// ---------------- K2: recompute tiles, apply rsqrt(da) weights, row-reduce, fused apply.
__global__ __launch_bounds__(256) void k2(const float* __restrict__ x,
                                          const float* __restrict__ pda,
                                          float* __restrict__ out) {
    __shared__ float Araw[16][132];
    __shared__ float Braw[64][132];
    __shared__ float w_s[NJ];
    __shared__ float scr_t0[4][16];
    __shared__ float scr_db[4][16];
    __shared__ float f_s[16];
    const int bid = blockIdx.x;
    const int n = bid / 17, ib = bid % 17;
    const int i0 = ib * 16;
    const int tid = threadIdx.x;
    const float* xn = x + (size_t)n * C_CH * T_LEN;

    {   // w_j = rsqrt(da_j)  (da >= 257, eps negligible)
        float da = 0.f;
        #pragma unroll
        for (int k = 0; k < 17; ++k) da += pda[((size_t)n * 17 + k) * NJ + tid];
        w_s[tid] = rsqrtf(da);
    }
    {   // stage A
        const int u = tid & 31, cg8 = tid >> 5;
        const int t = 2 * i0 + u;
        #pragma unroll
        for (int p = 0; p < 16; ++p) {
            const int c = cg8 * 16 + p;
            const float v = (t <= 512) ? xn[c * T_LEN + t] : 0.f;
            if (!(u & 1)) Araw[u >> 1][c] = v;
        }
    }
    __syncthreads();

    const int l = tid & 63, wv = tid >> 6, il = l & 15, g = l >> 4;
    bf16x8 ah[4], al[4];
    float psum = 0.f;
    #pragma unroll
    for (int kc = 0; kc < 4; ++kc) {
        const float* ap = &Araw[il][32 * kc + 8 * g];
        const float4 f0 = *(const float4*)ap, f1 = *(const float4*)(ap + 4);
        psum += dot8(f0, f1);
        cvt8(f0, f1, ah[kc], al[kc]);
    }
    psum += __shfl_xor(psum, 16, 64);
    psum += __shfl_xor(psum, 32, 64);
    float pv[4];
    #pragma unroll
    for (int r = 0; r < 4; ++r) pv[r] = __shfl(psum, 4 * g + r, 64);

    float t0r[4] = {0.f, 0.f, 0.f, 0.f};
    float dbr[4] = {0.f, 0.f, 0.f, 0.f};

    for (int ch = 0; ch < 4; ++ch) {
        __syncthreads();
        {
            const int u = tid & 31, cg8 = tid >> 5;
            #pragma unroll
            for (int p = 0; p < 16; ++p) {
                const int c = cg8 * 16 + p;
                #pragma unroll
                for (int s = 0; s < 4; ++s) {
                    const int uu = u + 32 * s;
                    const float v = xn[c * T_LEN + 128 * ch + uu];
                    if (uu & 1) Braw[uu >> 1][c] = v;
                }
            }
        }
        __syncthreads();
        bf16x8 bh[4], bl[4];
        float qsq = 0.f;
        #pragma unroll
        for (int kc = 0; kc < 4; ++kc) {
            const float* bp = &Braw[16 * wv + il][32 * kc + 8 * g];
            const float4 f0 = *(const float4*)bp, f1 = *(const float4*)(bp + 4);
            qsq += dot8(f0, f1);
            cvt8(f0, f1, bh[kc], bl[kc]);
        }
        qsq += __shfl_xor(qsq, 16, 64);
        qsq += __shfl_xor(qsq, 32, 64);

        f32x4 acc = {0.f, 0.f, 0.f, 0.f};
        #pragma unroll
        for (int kc = 0; kc < 4; ++kc) {
            acc = __builtin_amdgcn_mfma_f32_16x16x32_bf16(ah[kc], bh[kc], acc, 0, 0, 0);
            acc = __builtin_amdgcn_mfma_f32_16x16x32_bf16(ah[kc], bl[kc], acc, 0, 0, 0);
            acc = __builtin_amdgcn_mfma_f32_16x16x32_bf16(al[kc], bh[kc], acc, 0, 0, 0);
        }
        const float wj = w_s[64 * ch + 16 * wv + il];
        #pragma unroll
        for (int r = 0; r < 4; ++r) {
            const int i = i0 + 4 * g + r;
            const float rv = exp2f((pv[r] + qsq - 2.f * acc[r]) * SCALE);
            if (i < NI) { t0r[r] = fmaf(rv, wj, t0r[r]); dbr[r] += rv; }
        }
    }
    // reduce over 16 columns within wave (il bits), then across waves
    #pragma unroll
    for (int r = 0; r < 4; ++r) {
        #pragma unroll
        for (int off = 1; off < 16; off <<= 1) {
            t0r[r] += __shfl_xor(t0r[r], off, 64);
            dbr[r] += __shfl_xor(dbr[r], off, 64);
        }
    }
    if (il == 0) {
        #pragma unroll
        for (int r = 0; r < 4; ++r) {
            scr_t0[wv][4 * g + r] = t0r[r];
            scr_db[wv][4 * g + r] = dbr[r];
        }
    }
    __syncthreads();
    if (tid < 16) {
        const float t0 = scr_t0[0][tid] + scr_t0[1][tid] + scr_t0[2][tid] + scr_t0[3][tid];
        const float db = scr_db[0][tid] + scr_db[1][tid] + scr_db[2][tid] + scr_db[3][tid];
        f_s[tid] = 2.f * t0 * rsqrtf(db);
    }
    __syncthreads();
    // fused apply for this block's exclusive t-strip [2*i0, 2*i0+32)
    {
        const int tt = tid & 31, cgp = tid >> 5;
        const int t = 2 * i0 + tt;
        if (t <= 512) {
            const float f = f_s[tt >> 1];
            float* on = out + (size_t)n * C_CH * T_LEN;
            #pragma unroll
            for (int p = 0; p < 16; ++p) {
                const int c = cgp * 16 + p;
                on[c * T_LEN + t] = xn[c * T_LEN + t] * f;
            }
        }
    }
}

extern "C" void kernel_launch(void* const* d_in, const int* in_sizes, int n_in,
                              void* d_out, int out_size, void* d_ws, size_t ws_size,
                              hipStream_t stream) {
    const float* x = (const float*)d_in[0];
    float* out = (float*)d_out;
    float* pda = (float*)d_ws;

    k1<<<272, 256, 0, stream>>>(x, pda);
    k2<<<272, 256, 0, stream>>>(x, pda, out);
}